// Round 8
// baseline (262.998 us; speedup 1.0000x reference)
//
#include <hip/hip_runtime.h>

// TriplePairwiseCEFocalLoss: out = mean_b( cnt_b>0 ? sum_j(fl[b,j]*neg[b,j])/cnt_b : 0 )
//   neg[b,j] = (mask[b,j]==1) && j!=head[b] && j!=tail[b]
//   x = scores[b,j]-scores[b,tail[b]]; e=exp(x); sp=log(1+e); pt=1/(1+e)
//   fl = (1-pt)^2 * sp
//
// R7 post-mortem: nt loads broke the 100us plateau (focal dropped below the
// 77us poison fills; bench 288->260). L3-allocate path was the drag. The
// poison fill itself shows 6.9 TB/s one-direction write => fabric has
// headroom; test whether nt-READ scales with in-flight depth. R8: explicit
// static group schedule (load G0, load G1, compute G0, load G2, ...) with
// 128-VGPR budget (launch_bounds 256,4) so 8-16 nt loads stay in flight
// across each compute phase; integer cnt to trim VALU.

using f32x4 = __attribute__((ext_vector_type(4))) float;
using i32x4 = __attribute__((ext_vector_type(4))) int;

__device__ __forceinline__ float focal_term(float x) {
    const float e  = __expf(x);              // |x| <= ~11.2 for N(0,1) scores
    const float t  = 1.f + e;
    const float sp = __logf(t);              // softplus(x) = -logpt
    const float pt = __builtin_amdgcn_rcpf(t);
    const float om = 1.f - pt;
    return om * om * sp;
}

template <int S>
__global__ __launch_bounds__(256, 4) void focal_row_kernel(
    const float* __restrict__ scores,
    const int*   __restrict__ head_pos,
    const int*   __restrict__ tail_pos,
    const int*   __restrict__ mask,
    float*       __restrict__ row_out,
    int B)
{
    const int lane = threadIdx.x & 63;
    const int row  = blockIdx.x * 4 + (threadIdx.x >> 6);   // one wave per row
    if (row >= B) return;

    const int head = head_pos[row];
    const int tail = tail_pos[row];
    const float* srow = scores + (size_t)row * S;
    const int*   mrow = mask   + (size_t)row * S;
    const f32x4* s4 = reinterpret_cast<const f32x4*>(srow);
    const i32x4* m4 = reinterpret_cast<const i32x4*>(mrow);
    const float pos = srow[tail];

    constexpr int NV4 = S / 4 / 64;          // vec4 per lane (16 at S=4096)
    constexpr int G   = 4;                   // vec4 per group
    constexpr int NG  = NV4 / G;             // 4 groups
    static_assert(NV4 % G == 0 && NG >= 2, "shape");

    float fsum = 0.f;
    int   cnt  = 0;

    // static software pipeline: G_{i+1} loads in flight while G_i computes.
    f32x4 sA[G], sB[G]; i32x4 mA[G], mB[G];

    #pragma unroll
    for (int u = 0; u < G; ++u) {            // load G0 -> A
        const int v = lane + 64 * u;
        sA[u] = __builtin_nontemporal_load(&s4[v]);
        mA[u] = __builtin_nontemporal_load(&m4[v]);
    }

    #pragma unroll
    for (int g = 0; g < NG; ++g) {
        // issue next group's 8 nt loads before computing current group
        if (g + 1 < NG) {
            #pragma unroll
            for (int u = 0; u < G; ++u) {
                const int v = lane + 64 * ((g + 1) * G + u);
                if (g & 1) { sA[u] = __builtin_nontemporal_load(&s4[v]);
                             mA[u] = __builtin_nontemporal_load(&m4[v]); }
                else       { sB[u] = __builtin_nontemporal_load(&s4[v]);
                             mB[u] = __builtin_nontemporal_load(&m4[v]); }
            }
        }
        #pragma unroll
        for (int u = 0; u < G; ++u) {
            const f32x4 sv = (g & 1) ? sB[u] : sA[u];
            const i32x4 mv = (g & 1) ? mB[u] : mA[u];
            #pragma unroll
            for (int k = 0; k < 4; ++k) {
                const float fl = focal_term(sv[k] - pos);
                fsum += mv[k] ? fl : 0.f;    // mask in {0,1}; head/tail fixed below
                cnt  += mv[k];
            }
        }
    }

    // wave-level butterfly reduce (64 lanes)
    float fcnt = (float)cnt;
    #pragma unroll
    for (int off = 32; off; off >>= 1) {
        fsum += __shfl_down(fsum, off, 64);
        fcnt += __shfl_down(fcnt, off, 64);
    }

    if (lane == 0) {
        // remove head/tail elements counted as negatives (ref: m[head]=-1, m[tail]=-1)
        if (mrow[head] == 1) { fsum -= focal_term(srow[head] - pos); fcnt -= 1.f; }
        if (tail != head && mrow[tail] == 1) { fsum -= focal_term(0.f); fcnt -= 1.f; }
        row_out[row] = (fcnt > 0.f) ? fsum / fcnt : 0.f;
    }
}

// generic fallback (any S multiple of 4) — block-per-row, exact semantics
__global__ __launch_bounds__(256) void focal_row_generic(
    const float* __restrict__ scores,
    const int*   __restrict__ head_pos,
    const int*   __restrict__ tail_pos,
    const int*   __restrict__ mask,
    float*       __restrict__ row_out,
    int S)
{
    const int row  = blockIdx.x;
    const int tid  = threadIdx.x;
    const int head = head_pos[row];
    const int tail = tail_pos[row];
    const float* srow = scores + (size_t)row * S;
    const int*   mrow = mask   + (size_t)row * S;
    const float pos = srow[tail];
    float fsum = 0.f, cnt = 0.f;
    for (int idx = tid; idx < S; idx += 256) {
        const float fl = focal_term(srow[idx] - pos);
        if ((mrow[idx] == 1) && (idx != head) && (idx != tail)) { fsum += fl; cnt += 1.f; }
    }
    #pragma unroll
    for (int off = 32; off; off >>= 1) {
        fsum += __shfl_down(fsum, off, 64);
        cnt  += __shfl_down(cnt,  off, 64);
    }
    __shared__ float sf[4]; __shared__ float sc[4];
    const int wave = tid >> 6;
    if ((tid & 63) == 0) { sf[wave] = fsum; sc[wave] = cnt; }
    __syncthreads();
    if (tid == 0) {
        float tot = sf[0] + sf[1] + sf[2] + sf[3];
        float c   = sc[0] + sc[1] + sc[2] + sc[3];
        row_out[row] = (c > 0.f) ? tot / c : 0.f;
    }
}

__global__ __launch_bounds__(256) void final_reduce_kernel(
    const float* __restrict__ row_out, float* __restrict__ out, int B)
{
    float sum = 0.f;
    const float4* r4 = reinterpret_cast<const float4*>(row_out);
    const int nvec = B >> 2;
    for (int i = threadIdx.x; i < nvec; i += 256) {
        float4 v = r4[i];
        sum += (v.x + v.y) + (v.z + v.w);
    }
    #pragma unroll
    for (int off = 32; off; off >>= 1) sum += __shfl_down(sum, off, 64);
    __shared__ float sf[4];
    const int wave = threadIdx.x >> 6;
    if ((threadIdx.x & 63) == 0) sf[wave] = sum;
    __syncthreads();
    if (threadIdx.x == 0) out[0] = (sf[0] + sf[1] + sf[2] + sf[3]) / (float)B;
}

extern "C" void kernel_launch(void* const* d_in, const int* in_sizes, int n_in,
                              void* d_out, int out_size, void* d_ws, size_t ws_size,
                              hipStream_t stream)
{
    const float* scores = (const float*)d_in[0];
    const int*   headp  = (const int*)d_in[1];
    const int*   tailp  = (const int*)d_in[2];
    const int*   maskp  = (const int*)d_in[3];
    const int B = in_sizes[1];
    const int S = in_sizes[0] / B;

    float* rowbuf = (float*)d_ws;   // B floats scratch, fully rewritten each call
    float* out    = (float*)d_out;

    if (S == 4096) {
        const int grid = (B + 3) / 4;   // one 64-lane wave per row
        focal_row_kernel<4096><<<grid, 256, 0, stream>>>(scores, headp, tailp, maskp, rowbuf, B);
    } else {
        focal_row_generic<<<B, 256, 0, stream>>>(scores, headp, tailp, maskp, rowbuf, S);
    }
    final_reduce_kernel<<<1, 256, 0, stream>>>(rowbuf, out, B);
}